// Round 5
// baseline (207.115 us; speedup 1.0000x reference)
//
#include <hip/hip_runtime.h>

// TriangleAttentionStartingNode — MI355X gfx950. f32 global I/O, bf16 MFMA compute.
//
// R5: occupancy round. Head-split grid (h=4, i=256)=1024 blocks, 4 blocks/CU
// (LDS 36.9 KB, __launch_bounds__(256,4)). sZ eliminated: LN recomputed per-lane
// with cross-quad shuffle stats (4 shuffles). K/V LDS layouts permuted so every
// MFMA fragment is a single ds_read_b128. Cross-head reduction of the fused
// Wo projection via f32 atomicAdd into memset-zeroed d_out (bo added by h==0).
// Native exp2/rcp in hot paths. One __syncthreads total.
//
// Wb (d_in[6]) unused: its bias broadcasts along the softmax axis and cancels
// exactly (softmax shift invariance).

typedef unsigned short u16;
typedef unsigned int   u32;
typedef __bf16 bf16x8 __attribute__((ext_vector_type(8)));
typedef float  f32x4  __attribute__((ext_vector_type(4)));

union U8 { bf16x8 b; u32 u[4]; uint4 q; };

// round-half-up f32->bf16 pair pack: 2 adds + 1 v_perm
__device__ __forceinline__ u32 pk(float a, float b) {
  const u32 au = __float_as_uint(a) + 0x8000u;
  const u32 bu = __float_as_uint(b) + 0x8000u;
  return __builtin_amdgcn_perm(bu, au, 0x07060302u);  // {b.hi16, a.hi16}
}
__device__ __forceinline__ float lo16(u32 v) { return __uint_as_float(v << 16); }
__device__ __forceinline__ float hi16(u32 v) { return __uint_as_float(v & 0xffff0000u); }
__device__ __forceinline__ f32x4 mfma16(bf16x8 a, bf16x8 b, f32x4 c) {
  return __builtin_amdgcn_mfma_f32_16x16x32_bf16(a, b, c, 0, 0, 0);
}

#define LDK 40    // 80 B rows (16B-aligned b128; dword-stride 20: conflict-free passes)
#define LDV 264   // 528 B rows (16B-aligned b128; dword-stride 132: conflict-free passes)

__global__ __launch_bounds__(256, 4) void tri_attn_head(
    const float* __restrict__ z,  const float* __restrict__ ln_g, const float* __restrict__ ln_b,
    const float* __restrict__ Wq, const float* __restrict__ Wk,   const float* __restrict__ Wv,
    const float* __restrict__ Wg, const float* __restrict__ bg,
    const float* __restrict__ Wo, const float* __restrict__ bo,   float* __restrict__ out)
{
  // sKp[key][quad*8+j]: j=0..3 -> ch quad*4+j, j=4..7 -> ch 16+quad*4+(j-4)  (sigma)
  // sVtp[ch][chunk*32+quad*8+j]: j=0..3 -> key chunk+quad*4+j, j=4..7 -> +16   (sigma')
  __shared__ u16 sKp [256][LDK];
  __shared__ u16 sVtp[32][LDV];

  const int h    = blockIdx.x;
  const int i    = blockIdx.y;
  const int tid  = threadIdx.x;
  const int wave = tid >> 6, lane = tid & 63, quad = lane >> 4, col = lane & 15;
  const f32x4 z4 = {0.f, 0.f, 0.f, 0.f};

  // per-lane LN params for channels quad*8..+7
  float lg[8], lb[8];
  {
    const float4 g0 = *(const float4*)(ln_g + quad*8);
    const float4 g1 = *(const float4*)(ln_g + quad*8 + 4);
    const float4 b0 = *(const float4*)(ln_b + quad*8);
    const float4 b1 = *(const float4*)(ln_b + quad*8 + 4);
    lg[0]=g0.x; lg[1]=g0.y; lg[2]=g0.z; lg[3]=g0.w; lg[4]=g1.x; lg[5]=g1.y; lg[6]=g1.z; lg[7]=g1.w;
    lb[0]=b0.x; lb[1]=b0.y; lb[2]=b0.z; lb[3]=b0.w; lb[4]=b1.x; lb[5]=b1.y; lb[6]=b1.z; lb[7]=b1.w;
  }
  // weight fragments for this head (L2-hot)
  auto ldw = [&](const float* W, int cb) -> U8 {
    const float* p = W + h*1024 + (cb*16 + col)*32 + quad*8;
    const float4 a = *(const float4*)(p);
    const float4 b = *(const float4*)(p + 4);
    U8 t;
    t.u[0] = pk(a.x, a.y); t.u[1] = pk(a.z, a.w);
    t.u[2] = pk(b.x, b.y); t.u[3] = pk(b.z, b.w);
    return t;
  };
  const U8 WkF0 = ldw(Wk,0), WkF1 = ldw(Wk,1);
  const U8 WvF0 = ldw(Wv,0), WvF1 = ldw(Wv,1);
  const U8 WqF0 = ldw(Wq,0), WqF1 = ldw(Wq,1);
  const U8 WgF0 = ldw(Wg,0), WgF1 = ldw(Wg,1);
  float bgl[8];
#pragma unroll
  for (int r = 0; r < 4; r++) {
    bgl[r]     = bg[h*32 + quad*4 + r];
    bgl[4 + r] = bg[h*32 + 16 + quad*4 + r];
  }

  const float k2e = 0.17677669529663687f * 1.44269504089f;   // (1/sqrt32)*log2(e)
  U8  QB[4];      // pre-scaled Q, permuted-k B-frags (one per q-tile)
  u32 G16[4][4];  // gates, packed bf16 pairs, O^T C-layout order

  // ---------------- phase 1: LN (shuffle-stats) + projections ----------------
#pragma unroll
  for (int p = 0; p < 4; p++) {
    const int pbase = (p*4 + wave) * 16, pos = pbase + col;
    float x[8];
    {
      const float* zr = z + (((i << 8) + pos) << 5) + quad*8;
      const float4 a = *(const float4*)(zr);
      const float4 b = *(const float4*)(zr + 4);
      x[0]=a.x; x[1]=a.y; x[2]=a.z; x[3]=a.w; x[4]=b.x; x[5]=b.y; x[6]=b.z; x[7]=b.w;
    }
    float sx = 0.f, sq = 0.f;
#pragma unroll
    for (int e = 0; e < 8; e++) { sx += x[e]; sq = fmaf(x[e], x[e], sq); }
    sx += __shfl_xor(sx, 16);  sq += __shfl_xor(sq, 16);
    sx += __shfl_xor(sx, 32);  sq += __shfl_xor(sq, 32);
    const float mu   = sx * (1.f / 32.f);
    const float var  = sq * (1.f / 32.f) - mu * mu;
    const float rstd = rsqrtf(var + 1e-5f);
    U8 ZA;
#pragma unroll
    for (int e = 0; e < 4; e++) {
      ZA.u[e] = pk((x[2*e]   - mu) * rstd * lg[2*e]   + lb[2*e],
                   (x[2*e+1] - mu) * rstd * lg[2*e+1] + lb[2*e+1]);
    }
    // projections
    const f32x4 k0 = mfma16(WkF0.b, ZA.b, z4);   // K^T: ch=quad*4+r,    pos=col
    const f32x4 k1 = mfma16(WkF1.b, ZA.b, z4);   //      ch=16+quad*4+r
    const f32x4 v0 = mfma16(ZA.b, WvF0.b, z4);   // V:   pos=quad*4+r,   ch=col
    const f32x4 v1 = mfma16(ZA.b, WvF1.b, z4);   //                      ch=16+col
    const f32x4 q0 = mfma16(WqF0.b, ZA.b, z4);
    const f32x4 q1 = mfma16(WqF1.b, ZA.b, z4);
    const f32x4 g0 = mfma16(WgF0.b, ZA.b, z4);
    const f32x4 g1 = mfma16(WgF1.b, ZA.b, z4);
    // K: one b128 per lane in sigma order
    {
      U8 t;
      t.u[0] = pk(k0[0],k0[1]); t.u[1] = pk(k0[2],k0[3]);
      t.u[2] = pk(k1[0],k1[1]); t.u[3] = pk(k1[2],k1[3]);
      *(uint4*)&sKp[pos][quad*8] = t.q;
    }
    // V: two uint2 per lane into sigma' slots
    {
      const int base = (pbase & ~31) + quad*8 + ((pbase >> 2) & 4);   // chunk + quad*8 + sel*4
      *(uint2*)&sVtp[col][base]      = make_uint2(pk(v0[0],v0[1]), pk(v0[2],v0[3]));
      *(uint2*)&sVtp[16 + col][base] = make_uint2(pk(v1[0],v1[1]), pk(v1[2],v1[3]));
    }
    // Q (scale folded) and gate (packed bf16)
    QB[p].u[0] = pk(q0[0]*k2e, q0[1]*k2e); QB[p].u[1] = pk(q0[2]*k2e, q0[3]*k2e);
    QB[p].u[2] = pk(q1[0]*k2e, q1[1]*k2e); QB[p].u[3] = pk(q1[2]*k2e, q1[3]*k2e);
#pragma unroll
    for (int r = 0; r < 2; r++) {
      G16[p][r]   = pk(__builtin_amdgcn_rcpf(1.f + __expf(-(g0[2*r] + bgl[2*r]))),
                       __builtin_amdgcn_rcpf(1.f + __expf(-(g0[2*r+1] + bgl[2*r+1]))));
      G16[p][2+r] = pk(__builtin_amdgcn_rcpf(1.f + __expf(-(g1[2*r] + bgl[4+2*r]))),
                       __builtin_amdgcn_rcpf(1.f + __expf(-(g1[2*r+1] + bgl[4+2*r+1]))));
    }
  }
  __syncthreads();

  // ---- bo (added once, by h==0 blocks) ----
  const float bsel = (h == 0) ? 1.f : 0.f;
  float bo0[4], bo1[4];
#pragma unroll
  for (int r = 0; r < 4; r++) {
    bo0[r] = bo[quad*4 + r] * bsel;
    bo1[r] = bo[16 + quad*4 + r] * bsel;
  }

  // ---------------- phase 2: attention + fused Wo, atomic out ----------------
#pragma unroll
  for (int p = 0; p < 4; p++) {
    const int qbase = (p*4 + wave) * 16;
    float l = 0.f;
    f32x4 O0 = z4, O1 = z4;                 // O^T: ch=quad*4+r (+16), q=col
#pragma unroll
    for (int kb = 0; kb < 256; kb += 32) {
      U8 KF0, KF1;
      KF0.q = *(const uint4*)&sKp[kb + col][quad*8];
      KF1.q = *(const uint4*)&sKp[kb + 16 + col][quad*8];
      const f32x4 S0 = mfma16(KF0.b, QB[p].b, z4);   // keys kb+quad*4+r
      const f32x4 S1 = mfma16(KF1.b, QB[p].b, z4);   // keys kb+16+quad*4+r
      float ps[8];
#pragma unroll
      for (int r = 0; r < 4; r++) {
        ps[r]     = __builtin_amdgcn_exp2f(S0[r]);
        ps[4 + r] = __builtin_amdgcn_exp2f(S1[r]);
      }
      l += ((ps[0] + ps[1]) + (ps[2] + ps[3])) + ((ps[4] + ps[5]) + (ps[6] + ps[7]));
      U8 PB;
      PB.u[0] = pk(ps[0], ps[1]); PB.u[1] = pk(ps[2], ps[3]);
      PB.u[2] = pk(ps[4], ps[5]); PB.u[3] = pk(ps[6], ps[7]);
      U8 VF0, VF1;
      VF0.q = *(const uint4*)&sVtp[col][kb + quad*8];
      VF1.q = *(const uint4*)&sVtp[16 + col][kb + quad*8];
      O0 = mfma16(VF0.b, PB.b, O0);
      O1 = mfma16(VF1.b, PB.b, O1);
    }
    l += __shfl_xor(l, 16);
    l += __shfl_xor(l, 32);
    const float inv = __builtin_amdgcn_rcpf(l);
    float og[8];
    og[0] = O0[0]*inv*lo16(G16[p][0]); og[1] = O0[1]*inv*hi16(G16[p][0]);
    og[2] = O0[2]*inv*lo16(G16[p][1]); og[3] = O0[3]*inv*hi16(G16[p][1]);
    og[4] = O1[0]*inv*lo16(G16[p][2]); og[5] = O1[1]*inv*hi16(G16[p][2]);
    og[6] = O1[2]*inv*lo16(G16[p][3]); og[7] = O1[3]*inv*hi16(G16[p][3]);
    U8 OB;   // gated O^T as permuted-k B-frag (sigma over head-channels)
    OB.u[0] = pk(og[0], og[1]); OB.u[1] = pk(og[2], og[3]);
    OB.u[2] = pk(og[4], og[5]); OB.u[3] = pk(og[6], og[7]);
    // Wo A-frags with matching sigma permutation
    U8 WoA0, WoA1;
    {
      const float4 a = *(const float4*)(Wo + col*128 + h*32 + quad*4);
      const float4 b = *(const float4*)(Wo + col*128 + h*32 + 16 + quad*4);
      WoA0.u[0] = pk(a.x,a.y); WoA0.u[1] = pk(a.z,a.w);
      WoA0.u[2] = pk(b.x,b.y); WoA0.u[3] = pk(b.z,b.w);
      const float4 c = *(const float4*)(Wo + (16 + col)*128 + h*32 + quad*4);
      const float4 d = *(const float4*)(Wo + (16 + col)*128 + h*32 + 16 + quad*4);
      WoA1.u[0] = pk(c.x,c.y); WoA1.u[1] = pk(c.z,c.w);
      WoA1.u[2] = pk(d.x,d.y); WoA1.u[3] = pk(d.z,d.w);
    }
    const f32x4 a0 = mfma16(WoA0.b, OB.b, z4);   // D[cout=quad*4+r][q=col]
    const f32x4 a1 = mfma16(WoA1.b, OB.b, z4);   // couts 16..31
    float* op = out + (((i << 8) + qbase + col) << 5);
#pragma unroll
    for (int r = 0; r < 4; r++) {
      atomicAdd(op + quad*4 + r,      a0[r] + bo0[r]);
      atomicAdd(op + 16 + quad*4 + r, a1[r] + bo1[r]);
    }
  }
}

extern "C" void kernel_launch(void* const* d_in, const int* in_sizes, int n_in,
                              void* d_out, int out_size, void* d_ws, size_t ws_size,
                              hipStream_t stream)
{
  const float* z    = (const float*)d_in[0];
  const float* ln_g = (const float*)d_in[1];
  const float* ln_b = (const float*)d_in[2];
  const float* Wq   = (const float*)d_in[3];
  const float* Wk   = (const float*)d_in[4];
  const float* Wv   = (const float*)d_in[5];
  // d_in[6] = Wb: softmax shift invariance -> exactly cancels, unused.
  const float* Wg   = (const float*)d_in[7];
  const float* bg   = (const float*)d_in[8];
  const float* Wo   = (const float*)d_in[9];
  const float* bo   = (const float*)d_in[10];

  hipMemsetAsync(d_out, 0, (size_t)out_size * sizeof(float), stream);
  tri_attn_head<<<dim3(4, 256), 256, 0, stream>>>(z, ln_g, ln_b, Wq, Wk, Wv, Wg, bg, Wo, bo,
                                                  (float*)d_out);
}

// Round 6
// 192.897 us; speedup vs baseline: 1.0737x; 1.0737x over previous
//
#include <hip/hip_runtime.h>

// TriangleAttentionStartingNode — MI355X gfx950. f32 global I/O, bf16 MFMA compute.
//
// R6: occupancy WITHOUT atomics. R5's regression isolated to (a) f32 atomicAdd
// write-through (WRITE_SIZE 8->140 MB, waves parked on vmcnt) and (b) an 8-way
// LDS bank conflict in the b128 layout (SQ_LDS_BANK_CONFLICT 131k->2.2M).
// Fix: per-head gated output -> ws (plain bf16 stores), tiny MFMA out-proj
// kernel K2; LDS reverted to R4's measured-good b64 scheme.
//   K1: grid (h*2+qhalf = 8, i = 256) = 2048 blocks (4/CU), 256 thr.
//       LN via cross-quad shuffle stats; K,V proj (all 256 keys) -> LDS;
//       Q,G (own 128 queries) in regs; S^T flash (no max; scale*log2e folded
//       into Q); gated O^T -> go[pos][h*32+ch] bf16 in ws.
//   K2: grid 1024, 256 thr. out = go @ Wo^T + bo, MFMA, f32 stores.
// Fallback (ws_size < 16 MiB): R4's proven single fused kernel (52.6 us).
//
// Wb (d_in[6]) unused: bias broadcasts along the softmax axis and cancels.

typedef unsigned short u16;
typedef unsigned int   u32;
typedef __bf16 bf16x8 __attribute__((ext_vector_type(8)));
typedef float  f32x4  __attribute__((ext_vector_type(4)));

union U8 { bf16x8 b; u32 u[4]; uint4 q; };

// round-half-up f32->bf16 pair pack: 2 adds + 1 v_perm
__device__ __forceinline__ u32 pk(float a, float b) {
  const u32 au = __float_as_uint(a) + 0x8000u;
  const u32 bu = __float_as_uint(b) + 0x8000u;
  return __builtin_amdgcn_perm(bu, au, 0x07060302u);  // {b.hi16, a.hi16}
}
__device__ __forceinline__ f32x4 mfma16(bf16x8 a, bf16x8 b, f32x4 c) {
  return __builtin_amdgcn_mfma_f32_16x16x32_bf16(a, b, c, 0, 0, 0);
}

#define LDK 36    // 72 B rows — b64 scheme, measured low-conflict (R4)
#define LDV 260   // 520 B rows — b64 scheme, measured low-conflict (R4)

// ============================ K1: attention ============================
__global__ __launch_bounds__(256, 4) void tri_attn_k1(
    const float* __restrict__ z,  const float* __restrict__ ln_g, const float* __restrict__ ln_b,
    const float* __restrict__ Wq, const float* __restrict__ Wk,   const float* __restrict__ Wv,
    const float* __restrict__ Wg, const float* __restrict__ bg,   u16* __restrict__ go)
{
  __shared__ u16 sK [256][LDK];   // K[key][ch]    bf16
  __shared__ u16 sVt[32][LDV];    // V^T[ch][key]  bf16

  const int h     = blockIdx.x >> 1;
  const int qhalf = blockIdx.x & 1;
  const int i     = blockIdx.y;
  const int tid   = threadIdx.x;
  const int wave  = tid >> 6, lane = tid & 63, quad = lane >> 4, col = lane & 15;
  const f32x4 z4  = {0.f, 0.f, 0.f, 0.f};

  // per-lane LN params for channels quad*8..+7
  float lg[8], lb[8];
  {
    const float4 g0 = *(const float4*)(ln_g + quad*8);
    const float4 g1 = *(const float4*)(ln_g + quad*8 + 4);
    const float4 b0 = *(const float4*)(ln_b + quad*8);
    const float4 b1 = *(const float4*)(ln_b + quad*8 + 4);
    lg[0]=g0.x; lg[1]=g0.y; lg[2]=g0.z; lg[3]=g0.w; lg[4]=g1.x; lg[5]=g1.y; lg[6]=g1.z; lg[7]=g1.w;
    lb[0]=b0.x; lb[1]=b0.y; lb[2]=b0.z; lb[3]=b0.w; lb[4]=b1.x; lb[5]=b1.y; lb[6]=b1.z; lb[7]=b1.w;
  }
  auto ldw = [&](const float* W, int cb) -> U8 {
    const float* p = W + h*1024 + (cb*16 + col)*32 + quad*8;
    const float4 a = *(const float4*)(p);
    const float4 b = *(const float4*)(p + 4);
    U8 t;
    t.u[0] = pk(a.x, a.y); t.u[1] = pk(a.z, a.w);
    t.u[2] = pk(b.x, b.y); t.u[3] = pk(b.z, b.w);
    return t;
  };
  const U8 WkF0 = ldw(Wk,0), WkF1 = ldw(Wk,1);
  const U8 WvF0 = ldw(Wv,0), WvF1 = ldw(Wv,1);
  const U8 WqF0 = ldw(Wq,0), WqF1 = ldw(Wq,1);
  const U8 WgF0 = ldw(Wg,0), WgF1 = ldw(Wg,1);
  float bgl[8];
#pragma unroll
  for (int r = 0; r < 4; r++) {
    bgl[r]     = bg[h*32 + quad*4 + r];
    bgl[4 + r] = bg[h*32 + 16 + quad*4 + r];
  }

  const float k2e = 0.17677669529663687f * 1.44269504089f;   // (1/sqrt32)*log2(e)
  U8    QB[2];      // pre-scaled Q, permuted-k B-frags (own q-tiles)
  float G[2][8];    // gates, O^T C-layout order

  // ---------------- phase 1: LN (shuffle stats) + projections ----------------
#pragma unroll
  for (int p = 0; p < 4; p++) {
    const int pbase = (p*4 + wave) * 16, pos = pbase + col;
    float x[8];
    {
      const float* zr = z + (((i << 8) + pos) << 5) + quad*8;
      const float4 a = *(const float4*)(zr);
      const float4 b = *(const float4*)(zr + 4);
      x[0]=a.x; x[1]=a.y; x[2]=a.z; x[3]=a.w; x[4]=b.x; x[5]=b.y; x[6]=b.z; x[7]=b.w;
    }
    float sx = 0.f, sq = 0.f;
#pragma unroll
    for (int e = 0; e < 8; e++) { sx += x[e]; sq = fmaf(x[e], x[e], sq); }
    sx += __shfl_xor(sx, 16);  sq += __shfl_xor(sq, 16);
    sx += __shfl_xor(sx, 32);  sq += __shfl_xor(sq, 32);
    const float mu   = sx * (1.f / 32.f);
    const float var  = sq * (1.f / 32.f) - mu * mu;
    const float rstd = rsqrtf(var + 1e-5f);
    U8 ZA;
#pragma unroll
    for (int e = 0; e < 4; e++) {
      ZA.u[e] = pk((x[2*e]   - mu) * rstd * lg[2*e]   + lb[2*e],
                   (x[2*e+1] - mu) * rstd * lg[2*e+1] + lb[2*e+1]);
    }
    // K^T (ch=quad*4+r, pos=col), V (pos=quad*4+r, ch=col)
    const f32x4 k0 = mfma16(WkF0.b, ZA.b, z4);
    const f32x4 k1 = mfma16(WkF1.b, ZA.b, z4);
    const f32x4 v0 = mfma16(ZA.b, WvF0.b, z4);
    const f32x4 v1 = mfma16(ZA.b, WvF1.b, z4);
    *(uint2*)&sK[pos][quad*4]               = make_uint2(pk(k0[0],k0[1]), pk(k0[2],k0[3]));
    *(uint2*)&sK[pos][16 + quad*4]          = make_uint2(pk(k1[0],k1[1]), pk(k1[2],k1[3]));
    *(uint2*)&sVt[col][pbase + quad*4]      = make_uint2(pk(v0[0],v0[1]), pk(v0[2],v0[3]));
    *(uint2*)&sVt[16 + col][pbase + quad*4] = make_uint2(pk(v1[0],v1[1]), pk(v1[2],v1[3]));
    if ((p >> 1) == qhalf) {                 // own q-tile: Q and gate
      const int p2 = p & 1;
      const f32x4 q0 = mfma16(WqF0.b, ZA.b, z4);
      const f32x4 q1 = mfma16(WqF1.b, ZA.b, z4);
      const f32x4 g0 = mfma16(WgF0.b, ZA.b, z4);
      const f32x4 g1 = mfma16(WgF1.b, ZA.b, z4);
      QB[p2].u[0] = pk(q0[0]*k2e, q0[1]*k2e); QB[p2].u[1] = pk(q0[2]*k2e, q0[3]*k2e);
      QB[p2].u[2] = pk(q1[0]*k2e, q1[1]*k2e); QB[p2].u[3] = pk(q1[2]*k2e, q1[3]*k2e);
#pragma unroll
      for (int r = 0; r < 4; r++) {
        G[p2][r]     = 1.f / (1.f + __expf(-(g0[r] + bgl[r])));
        G[p2][4 + r] = 1.f / (1.f + __expf(-(g1[r] + bgl[4 + r])));
      }
    }
  }
  __syncthreads();

  // ---------------- phase 2: S^T flash, gated output -> ws ----------------
#pragma unroll
  for (int p2 = 0; p2 < 2; p2++) {
    float l = 0.f;
    f32x4 O0 = z4, O1 = z4;                 // O^T: ch=quad*4+r (+16), q=col
#pragma unroll
    for (int kb = 0; kb < 256; kb += 32) {
      U8 KF0, KF1;
      {
        const uint2 a = *(const uint2*)&sK[kb + col][quad*4];
        const uint2 b = *(const uint2*)&sK[kb + col][16 + quad*4];
        KF0.u[0] = a.x; KF0.u[1] = a.y; KF0.u[2] = b.x; KF0.u[3] = b.y;
        const uint2 c = *(const uint2*)&sK[kb + 16 + col][quad*4];
        const uint2 d = *(const uint2*)&sK[kb + 16 + col][16 + quad*4];
        KF1.u[0] = c.x; KF1.u[1] = c.y; KF1.u[2] = d.x; KF1.u[3] = d.y;
      }
      const f32x4 S0 = mfma16(KF0.b, QB[p2].b, z4);   // keys kb+quad*4+r
      const f32x4 S1 = mfma16(KF1.b, QB[p2].b, z4);   // keys kb+16+quad*4+r
      float ps[8];
#pragma unroll
      for (int r = 0; r < 4; r++) {
        ps[r]     = __builtin_amdgcn_exp2f(S0[r]);
        ps[4 + r] = __builtin_amdgcn_exp2f(S1[r]);
      }
      l += ((ps[0] + ps[1]) + (ps[2] + ps[3])) + ((ps[4] + ps[5]) + (ps[6] + ps[7]));
      U8 PB;
      PB.u[0] = pk(ps[0], ps[1]); PB.u[1] = pk(ps[2], ps[3]);
      PB.u[2] = pk(ps[4], ps[5]); PB.u[3] = pk(ps[6], ps[7]);
      U8 VF0, VF1;
      {
        const uint2 a = *(const uint2*)&sVt[col][kb + quad*4];
        const uint2 b = *(const uint2*)&sVt[col][kb + 16 + quad*4];
        VF0.u[0] = a.x; VF0.u[1] = a.y; VF0.u[2] = b.x; VF0.u[3] = b.y;
        const uint2 c = *(const uint2*)&sVt[16 + col][kb + quad*4];
        const uint2 d = *(const uint2*)&sVt[16 + col][kb + 16 + quad*4];
        VF1.u[0] = c.x; VF1.u[1] = c.y; VF1.u[2] = d.x; VF1.u[3] = d.y;
      }
      O0 = mfma16(VF0.b, PB.b, O0);
      O1 = mfma16(VF1.b, PB.b, O1);
    }
    l += __shfl_xor(l, 16);
    l += __shfl_xor(l, 32);
    const float inv = __builtin_amdgcn_rcpf(l);
    float og[8];
#pragma unroll
    for (int r = 0; r < 4; r++) {
      og[r]     = O0[r] * inv * G[p2][r];
      og[4 + r] = O1[r] * inv * G[p2][4 + r];
    }
    const int pos = (i << 8) + qhalf*128 + (p2*4 + wave)*16 + col;
    u16* gp = go + pos*128 + h*32;
    *(uint2*)(gp + quad*4)      = make_uint2(pk(og[0],og[1]), pk(og[2],og[3]));
    *(uint2*)(gp + 16 + quad*4) = make_uint2(pk(og[4],og[5]), pk(og[6],og[7]));
  }
}

// ============================ K2: out-projection ============================
// out[pos][cout] = sum_n go[pos][n] * Wo[cout][n] + bo[cout]
__global__ __launch_bounds__(256) void tri_out_proj(
    const u16* __restrict__ go, const float* __restrict__ Wo, const float* __restrict__ bo,
    float* __restrict__ out)
{
  const int tid  = threadIdx.x;
  const int wave = tid >> 6, lane = tid & 63, quad = lane >> 4, col = lane & 15;
  const int pbase = (blockIdx.x * 4 + wave) * 16;
  const f32x4 z4 = {0.f, 0.f, 0.f, 0.f};
  f32x4 a0 = z4, a1 = z4;
#pragma unroll
  for (int kc = 0; kc < 4; kc++) {
    U8 A, B0, B1;
    A.q = *(const uint4*)(go + (pbase + col)*128 + kc*32 + quad*8);
    {
      const float* p0 = Wo + col*128 + kc*32 + quad*8;
      const float4 x = *(const float4*)(p0);
      const float4 y = *(const float4*)(p0 + 4);
      B0.u[0] = pk(x.x,x.y); B0.u[1] = pk(x.z,x.w);
      B0.u[2] = pk(y.x,y.y); B0.u[3] = pk(y.z,y.w);
      const float* p1 = Wo + (16 + col)*128 + kc*32 + quad*8;
      const float4 u = *(const float4*)(p1);
      const float4 v = *(const float4*)(p1 + 4);
      B1.u[0] = pk(u.x,u.y); B1.u[1] = pk(u.z,u.w);
      B1.u[2] = pk(v.x,v.y); B1.u[3] = pk(v.z,v.w);
    }
    a0 = mfma16(A.b, B0.b, a0);   // D[pos=quad*4+r][cout=col]
    a1 = mfma16(A.b, B1.b, a1);   // couts 16..31
  }
  const float b0 = bo[col];
  const float b1 = bo[16 + col];
#pragma unroll
  for (int r = 0; r < 4; r++) {
    const int pos = pbase + quad*4 + r;
    out[pos*32 + col]      = a0[r] + b0;
    out[pos*32 + 16 + col] = a1[r] + b1;
  }
}

// ============================ fallback: R4 fused ============================
#define LDZ 40
__global__ __launch_bounds__(256) void tri_attn_fused(
    const float* __restrict__ z,  const float* __restrict__ ln_g, const float* __restrict__ ln_b,
    const float* __restrict__ Wq, const float* __restrict__ Wk,   const float* __restrict__ Wv,
    const float* __restrict__ Wg, const float* __restrict__ bg,
    const float* __restrict__ Wo, const float* __restrict__ bo,   float* __restrict__ out)
{
  __shared__ u16 sZ [256][LDZ];
  __shared__ u16 sK [256][LDK];
  __shared__ u16 sVt[32][LDV];
  const int qhalf = blockIdx.x;
  const int i     = blockIdx.y;
  const int tid   = threadIdx.x;
  const int wave  = tid >> 6, lane = tid & 63, quad = lane >> 4, col = lane & 15;
  const f32x4 z4  = {0.f, 0.f, 0.f, 0.f};
  {
    const float* zr = z + (((i << 8) + tid) << 5);
    float x[32];
#pragma unroll
    for (int e = 0; e < 8; e++) {
      const float4 v = *(const float4*)(zr + e*4);
      x[4*e] = v.x; x[4*e+1] = v.y; x[4*e+2] = v.z; x[4*e+3] = v.w;
    }
    float mu = 0.f;
#pragma unroll
    for (int c = 0; c < 32; c++) mu += x[c];
    mu *= (1.f / 32.f);
    float s2 = 0.f;
#pragma unroll
    for (int c = 0; c < 32; c++) { float d = x[c] - mu; s2 += d * d; }
    const float rstd = rsqrtf(s2 * (1.f / 32.f) + 1e-5f);
    u32* dst = (u32*)&sZ[tid][0];
#pragma unroll
    for (int e = 0; e < 16; e++) {
      dst[e] = pk((x[2*e]   - mu) * rstd * ln_g[2*e]   + ln_b[2*e],
                  (x[2*e+1] - mu) * rstd * ln_g[2*e+1] + ln_b[2*e+1]);
    }
  }
  __syncthreads();
  f32x4 acc[2][2] = {{z4, z4}, {z4, z4}};
  U8    QB[2];
  float G[2][8];
  const float k2e = 0.17677669529663687f * 1.44269504089f;
  for (int h = 0; h < 4; ++h) {
    auto ldw = [&](const float* W, int cb) -> U8 {
      const float* p = W + h*1024 + (cb*16 + col)*32 + quad*8;
      const float4 a = *(const float4*)(p);
      const float4 b = *(const float4*)(p + 4);
      U8 t;
      t.u[0] = pk(a.x, a.y); t.u[1] = pk(a.z, a.w);
      t.u[2] = pk(b.x, b.y); t.u[3] = pk(b.z, b.w);
      return t;
    };
    const U8 WkF0 = ldw(Wk,0), WkF1 = ldw(Wk,1);
    const U8 WvF0 = ldw(Wv,0), WvF1 = ldw(Wv,1);
    const U8 WqF0 = ldw(Wq,0), WqF1 = ldw(Wq,1);
    const U8 WgF0 = ldw(Wg,0), WgF1 = ldw(Wg,1);
    float bgl[8];
#pragma unroll
    for (int r = 0; r < 4; r++) {
      bgl[r]     = bg[h*32 + quad*4 + r];
      bgl[4 + r] = bg[h*32 + 16 + quad*4 + r];
    }
#pragma unroll
    for (int p = 0; p < 4; p++) {
      const int pbase = (p*4 + wave) * 16, row = pbase + col;
      U8 ZA;
      {
        const uint4 v = *(const uint4*)&sZ[row][quad*8];
        ZA.u[0] = v.x; ZA.u[1] = v.y; ZA.u[2] = v.z; ZA.u[3] = v.w;
      }
      const f32x4 k0 = mfma16(WkF0.b, ZA.b, z4);
      const f32x4 k1 = mfma16(WkF1.b, ZA.b, z4);
      const f32x4 v0 = mfma16(ZA.b, WvF0.b, z4);
      const f32x4 v1 = mfma16(ZA.b, WvF1.b, z4);
      *(uint2*)&sK[row][quad*4]               = make_uint2(pk(k0[0],k0[1]), pk(k0[2],k0[3]));
      *(uint2*)&sK[row][16 + quad*4]          = make_uint2(pk(k1[0],k1[1]), pk(k1[2],k1[3]));
      *(uint2*)&sVt[col][pbase + quad*4]      = make_uint2(pk(v0[0],v0[1]), pk(v0[2],v0[3]));
      *(uint2*)&sVt[16 + col][pbase + quad*4] = make_uint2(pk(v1[0],v1[1]), pk(v1[2],v1[3]));
      if ((p >> 1) == qhalf) {
        const int p2 = p & 1;
        const f32x4 q0 = mfma16(WqF0.b, ZA.b, z4);
        const f32x4 q1 = mfma16(WqF1.b, ZA.b, z4);
        const f32x4 g0 = mfma16(WgF0.b, ZA.b, z4);
        const f32x4 g1 = mfma16(WgF1.b, ZA.b, z4);
        QB[p2].u[0] = pk(q0[0]*k2e, q0[1]*k2e); QB[p2].u[1] = pk(q0[2]*k2e, q0[3]*k2e);
        QB[p2].u[2] = pk(q1[0]*k2e, q1[1]*k2e); QB[p2].u[3] = pk(q1[2]*k2e, q1[3]*k2e);
#pragma unroll
        for (int r = 0; r < 4; r++) {
          G[p2][r]     = 1.f / (1.f + __expf(-(g0[r] + bgl[r])));
          G[p2][4 + r] = 1.f / (1.f + __expf(-(g1[r] + bgl[4 + r])));
        }
      }
    }
    __syncthreads();
#pragma unroll
    for (int p2 = 0; p2 < 2; p2++) {
      float l = 0.f;
      f32x4 O0 = z4, O1 = z4;
#pragma unroll
      for (int kb = 0; kb < 256; kb += 32) {
        U8 KF0, KF1;
        {
          const uint2 a = *(const uint2*)&sK[kb + col][quad*4];
          const uint2 b = *(const uint2*)&sK[kb + col][16 + quad*4];
          KF0.u[0] = a.x; KF0.u[1] = a.y; KF0.u[2] = b.x; KF0.u[3] = b.y;
          const uint2 c = *(const uint2*)&sK[kb + 16 + col][quad*4];
          const uint2 d = *(const uint2*)&sK[kb + 16 + col][16 + quad*4];
          KF1.u[0] = c.x; KF1.u[1] = c.y; KF1.u[2] = d.x; KF1.u[3] = d.y;
        }
        const f32x4 S0 = mfma16(KF0.b, QB[p2].b, z4);
        const f32x4 S1 = mfma16(KF1.b, QB[p2].b, z4);
        float ps[8];
#pragma unroll
        for (int r = 0; r < 4; r++) {
          ps[r]     = __builtin_amdgcn_exp2f(S0[r]);
          ps[4 + r] = __builtin_amdgcn_exp2f(S1[r]);
        }
        l += ((ps[0] + ps[1]) + (ps[2] + ps[3])) + ((ps[4] + ps[5]) + (ps[6] + ps[7]));
        U8 PB;
        PB.u[0] = pk(ps[0], ps[1]); PB.u[1] = pk(ps[2], ps[3]);
        PB.u[2] = pk(ps[4], ps[5]); PB.u[3] = pk(ps[6], ps[7]);
        U8 VF0, VF1;
        {
          const uint2 a = *(const uint2*)&sVt[col][kb + quad*4];
          const uint2 b = *(const uint2*)&sVt[col][kb + 16 + quad*4];
          VF0.u[0] = a.x; VF0.u[1] = a.y; VF0.u[2] = b.x; VF0.u[3] = b.y;
          const uint2 c = *(const uint2*)&sVt[16 + col][kb + quad*4];
          const uint2 d = *(const uint2*)&sVt[16 + col][kb + 16 + quad*4];
          VF1.u[0] = c.x; VF1.u[1] = c.y; VF1.u[2] = d.x; VF1.u[3] = d.y;
        }
        O0 = mfma16(VF0.b, PB.b, O0);
        O1 = mfma16(VF1.b, PB.b, O1);
      }
      l += __shfl_xor(l, 16);
      l += __shfl_xor(l, 32);
      const float inv = 1.f / l;
      float og[8];
#pragma unroll
      for (int r = 0; r < 4; r++) {
        og[r]     = O0[r] * inv * G[p2][r];
        og[4 + r] = O1[r] * inv * G[p2][4 + r];
      }
      U8 OB;
      OB.u[0] = pk(og[0], og[1]); OB.u[1] = pk(og[2], og[3]);
      OB.u[2] = pk(og[4], og[5]); OB.u[3] = pk(og[6], og[7]);
      U8 WoA0, WoA1;
      {
        const float4 a = *(const float4*)(Wo + col*128 + h*32 + quad*4);
        const float4 b = *(const float4*)(Wo + col*128 + h*32 + 16 + quad*4);
        WoA0.u[0] = pk(a.x,a.y); WoA0.u[1] = pk(a.z,a.w);
        WoA0.u[2] = pk(b.x,b.y); WoA0.u[3] = pk(b.z,b.w);
        const float4 c = *(const float4*)(Wo + (16 + col)*128 + h*32 + quad*4);
        const float4 d = *(const float4*)(Wo + (16 + col)*128 + h*32 + 16 + quad*4);
        WoA1.u[0] = pk(c.x,c.y); WoA1.u[1] = pk(c.z,c.w);
        WoA1.u[2] = pk(d.x,d.y); WoA1.u[3] = pk(d.z,d.w);
      }
      acc[p2][0] = mfma16(WoA0.b, OB.b, acc[p2][0]);
      acc[p2][1] = mfma16(WoA1.b, OB.b, acc[p2][1]);
    }
    __syncthreads();
  }
  float bo0[4], bo1[4];
#pragma unroll
  for (int r = 0; r < 4; r++) {
    bo0[r] = bo[quad*4 + r];
    bo1[r] = bo[16 + quad*4 + r];
  }
#pragma unroll
  for (int p2 = 0; p2 < 2; p2++) {
    const int pos = (i << 8) + qhalf*128 + (p2*4 + wave)*16 + col;
    float* op = out + pos*32;
    *(float4*)(op + quad*4)      = make_float4(acc[p2][0][0] + bo0[0], acc[p2][0][1] + bo0[1],
                                               acc[p2][0][2] + bo0[2], acc[p2][0][3] + bo0[3]);
    *(float4*)(op + 16 + quad*4) = make_float4(acc[p2][1][0] + bo1[0], acc[p2][1][1] + bo1[1],
                                               acc[p2][1][2] + bo1[2], acc[p2][1][3] + bo1[3]);
  }
}

extern "C" void kernel_launch(void* const* d_in, const int* in_sizes, int n_in,
                              void* d_out, int out_size, void* d_ws, size_t ws_size,
                              hipStream_t stream)
{
  const float* z    = (const float*)d_in[0];
  const float* ln_g = (const float*)d_in[1];
  const float* ln_b = (const float*)d_in[2];
  const float* Wq   = (const float*)d_in[3];
  const float* Wk   = (const float*)d_in[4];
  const float* Wv   = (const float*)d_in[5];
  // d_in[6] = Wb: softmax shift invariance -> exactly cancels, unused.
  const float* Wg   = (const float*)d_in[7];
  const float* bg   = (const float*)d_in[8];
  const float* Wo   = (const float*)d_in[9];
  const float* bo   = (const float*)d_in[10];

  const size_t need = (size_t)65536 * 128 * sizeof(u16);   // 16 MiB go buffer
  if (ws_size >= need) {
    u16* go = (u16*)d_ws;
    tri_attn_k1<<<dim3(8, 256), 256, 0, stream>>>(z, ln_g, ln_b, Wq, Wk, Wv, Wg, bg, go);
    tri_out_proj<<<dim3(1024), 256, 0, stream>>>(go, Wo, bo, (float*)d_out);
  } else {
    tri_attn_fused<<<dim3(2, 256), 256, 0, stream>>>(z, ln_g, ln_b, Wq, Wk, Wv, Wg, bg, Wo, bo,
                                                     (float*)d_out);
  }
}

// Round 7
// 147.466 us; speedup vs baseline: 1.4045x; 1.3081x over previous
//
#include <hip/hip_runtime.h>

// TriangleAttentionStartingNode — MI355X gfx950. f32 global I/O, bf16 MFMA compute.
//
// R7: fix ws write amplification. R6 evidence: per-lane 8-B scattered uint2
// stores to ws hit HBM as full 128-B line RMWs (WRITE 254 MB for 16 MB logical,
// = 1024 stores/block x 128 B). Fix: head-major go[h][pos][32] + LDS-transpose
// staging (reusing dead sK) so final ws stores are uint4/lane, 1 KB contiguous
// per wave instruction (full-line coverage -> no partial sectors / RFO).
// Grid (h=4, i=256)=1024 blocks, 4/CU: projections once per head, z traffic
// halved vs R6. K2 contracts over heads from the head-major slab (16 B/lane
// coalesced reads). Fallback for ws_size<16MiB: R4 proven fused kernel.
//
// Wb (d_in[6]) unused: bias broadcasts along the softmax axis and cancels.

typedef unsigned short u16;
typedef unsigned int   u32;
typedef __bf16 bf16x8 __attribute__((ext_vector_type(8)));
typedef float  f32x4  __attribute__((ext_vector_type(4)));

union U8 { bf16x8 b; u32 u[4]; uint4 q; };

// round-half-up f32->bf16 pair pack: 2 adds + 1 v_perm
__device__ __forceinline__ u32 pk(float a, float b) {
  const u32 au = __float_as_uint(a) + 0x8000u;
  const u32 bu = __float_as_uint(b) + 0x8000u;
  return __builtin_amdgcn_perm(bu, au, 0x07060302u);  // {b.hi16, a.hi16}
}
__device__ __forceinline__ float lo16(u32 v) { return __uint_as_float(v << 16); }
__device__ __forceinline__ float hi16(u32 v) { return __uint_as_float(v & 0xffff0000u); }
__device__ __forceinline__ f32x4 mfma16(bf16x8 a, bf16x8 b, f32x4 c) {
  return __builtin_amdgcn_mfma_f32_16x16x32_bf16(a, b, c, 0, 0, 0);
}

#define LDK 36    // 72 B rows — b64 scheme, measured low-conflict (R4)
#define LDV 260   // 520 B rows — b64 scheme, measured low-conflict (R4)

// ============================ K1: attention ============================
__global__ __launch_bounds__(256, 4) void tri_attn_k1(
    const float* __restrict__ z,  const float* __restrict__ ln_g, const float* __restrict__ ln_b,
    const float* __restrict__ Wq, const float* __restrict__ Wk,   const float* __restrict__ Wv,
    const float* __restrict__ Wg, const float* __restrict__ bg,   u16* __restrict__ go)
{
  __shared__ u16 sK [256][LDK];   // K[key][ch] bf16; reused as output staging
  __shared__ u16 sVt[32][LDV];    // V^T[ch][key] bf16

  const int h    = blockIdx.x;
  const int i    = blockIdx.y;
  const int tid  = threadIdx.x;
  const int wave = tid >> 6, lane = tid & 63, quad = lane >> 4, col = lane & 15;
  const f32x4 z4 = {0.f, 0.f, 0.f, 0.f};

  // per-lane LN params for channels quad*8..+7
  float lg[8], lb[8];
  {
    const float4 g0 = *(const float4*)(ln_g + quad*8);
    const float4 g1 = *(const float4*)(ln_g + quad*8 + 4);
    const float4 b0 = *(const float4*)(ln_b + quad*8);
    const float4 b1 = *(const float4*)(ln_b + quad*8 + 4);
    lg[0]=g0.x; lg[1]=g0.y; lg[2]=g0.z; lg[3]=g0.w; lg[4]=g1.x; lg[5]=g1.y; lg[6]=g1.z; lg[7]=g1.w;
    lb[0]=b0.x; lb[1]=b0.y; lb[2]=b0.z; lb[3]=b0.w; lb[4]=b1.x; lb[5]=b1.y; lb[6]=b1.z; lb[7]=b1.w;
  }
  auto ldw = [&](const float* W, int cb) -> U8 {
    const float* p = W + h*1024 + (cb*16 + col)*32 + quad*8;
    const float4 a = *(const float4*)(p);
    const float4 b = *(const float4*)(p + 4);
    U8 t;
    t.u[0] = pk(a.x, a.y); t.u[1] = pk(a.z, a.w);
    t.u[2] = pk(b.x, b.y); t.u[3] = pk(b.z, b.w);
    return t;
  };
  const U8 WkF0 = ldw(Wk,0), WkF1 = ldw(Wk,1);
  const U8 WvF0 = ldw(Wv,0), WvF1 = ldw(Wv,1);
  const U8 WqF0 = ldw(Wq,0), WqF1 = ldw(Wq,1);
  const U8 WgF0 = ldw(Wg,0), WgF1 = ldw(Wg,1);
  float bgl[8];
#pragma unroll
  for (int r = 0; r < 4; r++) {
    bgl[r]     = bg[h*32 + quad*4 + r];
    bgl[4 + r] = bg[h*32 + 16 + quad*4 + r];
  }

  const float k2e = 0.17677669529663687f * 1.44269504089f;   // (1/sqrt32)*log2(e)
  U8  QB[4];       // pre-scaled Q, permuted-k B-frags
  u32 G16[4][4];   // gates, packed bf16 pairs, O^T C-layout order

  // ---------------- phase 1: LN (shuffle stats) + projections ----------------
#pragma unroll
  for (int p = 0; p < 4; p++) {
    const int pbase = (p*4 + wave) * 16, pos = pbase + col;
    float x[8];
    {
      const float* zr = z + (((i << 8) + pos) << 5) + quad*8;
      const float4 a = *(const float4*)(zr);
      const float4 b = *(const float4*)(zr + 4);
      x[0]=a.x; x[1]=a.y; x[2]=a.z; x[3]=a.w; x[4]=b.x; x[5]=b.y; x[6]=b.z; x[7]=b.w;
    }
    float sx = 0.f, sq = 0.f;
#pragma unroll
    for (int e = 0; e < 8; e++) { sx += x[e]; sq = fmaf(x[e], x[e], sq); }
    sx += __shfl_xor(sx, 16);  sq += __shfl_xor(sq, 16);
    sx += __shfl_xor(sx, 32);  sq += __shfl_xor(sq, 32);
    const float mu   = sx * (1.f / 32.f);
    const float var  = sq * (1.f / 32.f) - mu * mu;
    const float rstd = rsqrtf(var + 1e-5f);
    U8 ZA;
#pragma unroll
    for (int e = 0; e < 4; e++) {
      ZA.u[e] = pk((x[2*e]   - mu) * rstd * lg[2*e]   + lb[2*e],
                   (x[2*e+1] - mu) * rstd * lg[2*e+1] + lb[2*e+1]);
    }
    // K^T (ch=quad*4+r, pos=col), V (pos=quad*4+r, ch=col)
    const f32x4 k0 = mfma16(WkF0.b, ZA.b, z4);
    const f32x4 k1 = mfma16(WkF1.b, ZA.b, z4);
    const f32x4 v0 = mfma16(ZA.b, WvF0.b, z4);
    const f32x4 v1 = mfma16(ZA.b, WvF1.b, z4);
    const f32x4 q0 = mfma16(WqF0.b, ZA.b, z4);
    const f32x4 q1 = mfma16(WqF1.b, ZA.b, z4);
    const f32x4 g0 = mfma16(WgF0.b, ZA.b, z4);
    const f32x4 g1 = mfma16(WgF1.b, ZA.b, z4);
    *(uint2*)&sK[pos][quad*4]               = make_uint2(pk(k0[0],k0[1]), pk(k0[2],k0[3]));
    *(uint2*)&sK[pos][16 + quad*4]          = make_uint2(pk(k1[0],k1[1]), pk(k1[2],k1[3]));
    *(uint2*)&sVt[col][pbase + quad*4]      = make_uint2(pk(v0[0],v0[1]), pk(v0[2],v0[3]));
    *(uint2*)&sVt[16 + col][pbase + quad*4] = make_uint2(pk(v1[0],v1[1]), pk(v1[2],v1[3]));
    QB[p].u[0] = pk(q0[0]*k2e, q0[1]*k2e); QB[p].u[1] = pk(q0[2]*k2e, q0[3]*k2e);
    QB[p].u[2] = pk(q1[0]*k2e, q1[1]*k2e); QB[p].u[3] = pk(q1[2]*k2e, q1[3]*k2e);
#pragma unroll
    for (int r = 0; r < 2; r++) {
      G16[p][r]   = pk(1.f / (1.f + __expf(-(g0[2*r]   + bgl[2*r]))),
                       1.f / (1.f + __expf(-(g0[2*r+1] + bgl[2*r+1]))));
      G16[p][2+r] = pk(1.f / (1.f + __expf(-(g1[2*r]   + bgl[4+2*r]))),
                       1.f / (1.f + __expf(-(g1[2*r+1] + bgl[4+2*r+1]))));
    }
  }
  __syncthreads();

  // ---------------- phase 2: S^T flash; gated output kept in regs ----------------
  u32 OGP[4][4];   // gated O^T, packed bf16, per q-tile
#pragma unroll
  for (int p = 0; p < 4; p++) {
    float l = 0.f;
    f32x4 O0 = z4, O1 = z4;                 // O^T: ch=quad*4+r (+16), q=col
#pragma unroll
    for (int kb = 0; kb < 256; kb += 32) {
      U8 KF0, KF1;
      {
        const uint2 a = *(const uint2*)&sK[kb + col][quad*4];
        const uint2 b = *(const uint2*)&sK[kb + col][16 + quad*4];
        KF0.u[0] = a.x; KF0.u[1] = a.y; KF0.u[2] = b.x; KF0.u[3] = b.y;
        const uint2 c = *(const uint2*)&sK[kb + 16 + col][quad*4];
        const uint2 d = *(const uint2*)&sK[kb + 16 + col][16 + quad*4];
        KF1.u[0] = c.x; KF1.u[1] = c.y; KF1.u[2] = d.x; KF1.u[3] = d.y;
      }
      const f32x4 S0 = mfma16(KF0.b, QB[p].b, z4);   // keys kb+quad*4+r
      const f32x4 S1 = mfma16(KF1.b, QB[p].b, z4);   // keys kb+16+quad*4+r
      float ps[8];
#pragma unroll
      for (int r = 0; r < 4; r++) {
        ps[r]     = __builtin_amdgcn_exp2f(S0[r]);
        ps[4 + r] = __builtin_amdgcn_exp2f(S1[r]);
      }
      l += ((ps[0] + ps[1]) + (ps[2] + ps[3])) + ((ps[4] + ps[5]) + (ps[6] + ps[7]));
      U8 PB;
      PB.u[0] = pk(ps[0], ps[1]); PB.u[1] = pk(ps[2], ps[3]);
      PB.u[2] = pk(ps[4], ps[5]); PB.u[3] = pk(ps[6], ps[7]);
      U8 VF0, VF1;
      {
        const uint2 a = *(const uint2*)&sVt[col][kb + quad*4];
        const uint2 b = *(const uint2*)&sVt[col][kb + 16 + quad*4];
        VF0.u[0] = a.x; VF0.u[1] = a.y; VF0.u[2] = b.x; VF0.u[3] = b.y;
        const uint2 c = *(const uint2*)&sVt[16 + col][kb + quad*4];
        const uint2 d = *(const uint2*)&sVt[16 + col][kb + 16 + quad*4];
        VF1.u[0] = c.x; VF1.u[1] = c.y; VF1.u[2] = d.x; VF1.u[3] = d.y;
      }
      O0 = mfma16(VF0.b, PB.b, O0);
      O1 = mfma16(VF1.b, PB.b, O1);
    }
    l += __shfl_xor(l, 16);
    l += __shfl_xor(l, 32);
    const float inv = __builtin_amdgcn_rcpf(l);
    OGP[p][0] = pk(O0[0]*inv*lo16(G16[p][0]), O0[1]*inv*hi16(G16[p][0]));
    OGP[p][1] = pk(O0[2]*inv*lo16(G16[p][1]), O0[3]*inv*hi16(G16[p][1]));
    OGP[p][2] = pk(O1[0]*inv*lo16(G16[p][2]), O1[1]*inv*hi16(G16[p][2]));
    OGP[p][3] = pk(O1[2]*inv*lo16(G16[p][3]), O1[3]*inv*hi16(G16[p][3]));
  }
  __syncthreads();            // all waves done reading sK -> reuse as staging

  // ---------------- phase 3: LDS transpose -> coalesced uint4 ws stores ----------------
  u16 (*sOut)[LDK] = sK;      // sOut[pos][ch], stride 36
#pragma unroll
  for (int p = 0; p < 4; p++) {
    const int pos = (p*4 + wave)*16 + col;
    *(uint2*)&sOut[pos][quad*4]      = make_uint2(OGP[p][0], OGP[p][1]);
    *(uint2*)&sOut[pos][16 + quad*4] = make_uint2(OGP[p][2], OGP[p][3]);
  }
  __syncthreads();
  {
    u16* gh = go + ((h << 16) + (i << 8)) * 32;     // go[h][i*256][32]
    const int chunk = (tid & 3) * 8;                // 8 channels = 16 B
#pragma unroll
    for (int r = 0; r < 4; r++) {
      const int pos = r*64 + (tid >> 2);
      const uint2 a = *(const uint2*)&sOut[pos][chunk];
      const uint2 b = *(const uint2*)&sOut[pos][chunk + 4];
      *(uint4*)(gh + pos*32 + chunk) = make_uint4(a.x, a.y, b.x, b.y);  // 16 B/lane, 1 KB/wave
    }
  }
}

// ============================ K2: out-projection ============================
// out[pos][cout] = sum_h sum_ch go[h][pos][ch] * Wo[cout][h*32+ch] + bo[cout]
__global__ __launch_bounds__(256) void tri_out_proj(
    const u16* __restrict__ go, const float* __restrict__ Wo, const float* __restrict__ bo,
    float* __restrict__ out)
{
  const int tid  = threadIdx.x;
  const int wave = tid >> 6, lane = tid & 63, quad = lane >> 4, col = lane & 15;
  const int pbase = (blockIdx.x * 4 + wave) * 16;
  const f32x4 z4 = {0.f, 0.f, 0.f, 0.f};
  f32x4 a0 = z4, a1 = z4;
#pragma unroll
  for (int h = 0; h < 4; h++) {
    U8 A, B0, B1;
    A.q = *(const uint4*)(go + (h << 21) + (pbase + col)*32 + quad*8);   // h*65536*32
    {
      const float* p0 = Wo + col*128 + h*32 + quad*8;
      const float4 x = *(const float4*)(p0);
      const float4 y = *(const float4*)(p0 + 4);
      B0.u[0] = pk(x.x,x.y); B0.u[1] = pk(x.z,x.w);
      B0.u[2] = pk(y.x,y.y); B0.u[3] = pk(y.z,y.w);
      const float* p1 = Wo + (16 + col)*128 + h*32 + quad*8;
      const float4 u = *(const float4*)(p1);
      const float4 v = *(const float4*)(p1 + 4);
      B1.u[0] = pk(u.x,u.y); B1.u[1] = pk(u.z,u.w);
      B1.u[2] = pk(v.x,v.y); B1.u[3] = pk(v.z,v.w);
    }
    a0 = mfma16(A.b, B0.b, a0);   // D[pos=quad*4+r][cout=col]
    a1 = mfma16(A.b, B1.b, a1);   // couts 16..31
  }
  const float b0 = bo[col];
  const float b1 = bo[16 + col];
#pragma unroll
  for (int r = 0; r < 4; r++) {
    const int pos = pbase + quad*4 + r;
    out[pos*32 + col]      = a0[r] + b0;
    out[pos*32 + 16 + col] = a1[r] + b1;
  }
}

// ============================ fallback: R4 fused ============================
#define LDZ 40
__global__ __launch_bounds__(256) void tri_attn_fused(
    const float* __restrict__ z,  const float* __restrict__ ln_g, const float* __restrict__ ln_b,
    const float* __restrict__ Wq, const float* __restrict__ Wk,   const float* __restrict__ Wv,
    const float* __restrict__ Wg, const float* __restrict__ bg,
    const float* __restrict__ Wo, const float* __restrict__ bo,   float* __restrict__ out)
{
  __shared__ u16 sZ [256][LDZ];
  __shared__ u16 sK [256][LDK];
  __shared__ u16 sVt[32][LDV];
  const int qhalf = blockIdx.x;
  const int i     = blockIdx.y;
  const int tid   = threadIdx.x;
  const int wave  = tid >> 6, lane = tid & 63, quad = lane >> 4, col = lane & 15;
  const f32x4 z4  = {0.f, 0.f, 0.f, 0.f};
  {
    const float* zr = z + (((i << 8) + tid) << 5);
    float x[32];
#pragma unroll
    for (int e = 0; e < 8; e++) {
      const float4 v = *(const float4*)(zr + e*4);
      x[4*e] = v.x; x[4*e+1] = v.y; x[4*e+2] = v.z; x[4*e+3] = v.w;
    }
    float mu = 0.f;
#pragma unroll
    for (int c = 0; c < 32; c++) mu += x[c];
    mu *= (1.f / 32.f);
    float s2 = 0.f;
#pragma unroll
    for (int c = 0; c < 32; c++) { float d = x[c] - mu; s2 += d * d; }
    const float rstd = rsqrtf(s2 * (1.f / 32.f) + 1e-5f);
    u32* dst = (u32*)&sZ[tid][0];
#pragma unroll
    for (int e = 0; e < 16; e++) {
      dst[e] = pk((x[2*e]   - mu) * rstd * ln_g[2*e]   + ln_b[2*e],
                  (x[2*e+1] - mu) * rstd * ln_g[2*e+1] + ln_b[2*e+1]);
    }
  }
  __syncthreads();
  f32x4 acc[2][2] = {{z4, z4}, {z4, z4}};
  U8    QB[2];
  float G[2][8];
  const float k2e = 0.17677669529663687f * 1.44269504089f;
  for (int h = 0; h < 4; ++h) {
    auto ldw = [&](const float* W, int cb) -> U8 {
      const float* p = W + h*1024 + (cb*16 + col)*32 + quad*8;
      const float4 a = *(const float4*)(p);
      const float4 b = *(const float4*)(p + 4);
      U8 t;
      t.u[0] = pk(a.x, a.y); t.u[1] = pk(a.z, a.w);
      t.u[2] = pk(b.x, b.y); t.u[3] = pk(b.z, b.w);
      return t;
    };
    const U8 WkF0 = ldw(Wk,0), WkF1 = ldw(Wk,1);
    const U8 WvF0 = ldw(Wv,0), WvF1 = ldw(Wv,1);
    const U8 WqF0 = ldw(Wq,0), WqF1 = ldw(Wq,1);
    const U8 WgF0 = ldw(Wg,0), WgF1 = ldw(Wg,1);
    float bgl[8];
#pragma unroll
    for (int r = 0; r < 4; r++) {
      bgl[r]     = bg[h*32 + quad*4 + r];
      bgl[4 + r] = bg[h*32 + 16 + quad*4 + r];
    }
#pragma unroll
    for (int p = 0; p < 4; p++) {
      const int pbase = (p*4 + wave) * 16, row = pbase + col;
      U8 ZA;
      {
        const uint4 v = *(const uint4*)&sZ[row][quad*8];
        ZA.u[0] = v.x; ZA.u[1] = v.y; ZA.u[2] = v.z; ZA.u[3] = v.w;
      }
      const f32x4 k0 = mfma16(WkF0.b, ZA.b, z4);
      const f32x4 k1 = mfma16(WkF1.b, ZA.b, z4);
      const f32x4 v0 = mfma16(ZA.b, WvF0.b, z4);
      const f32x4 v1 = mfma16(ZA.b, WvF1.b, z4);
      *(uint2*)&sK[row][quad*4]               = make_uint2(pk(k0[0],k0[1]), pk(k0[2],k0[3]));
      *(uint2*)&sK[row][16 + quad*4]          = make_uint2(pk(k1[0],k1[1]), pk(k1[2],k1[3]));
      *(uint2*)&sVt[col][pbase + quad*4]      = make_uint2(pk(v0[0],v0[1]), pk(v0[2],v0[3]));
      *(uint2*)&sVt[16 + col][pbase + quad*4] = make_uint2(pk(v1[0],v1[1]), pk(v1[2],v1[3]));
      if ((p >> 1) == qhalf) {
        const int p2 = p & 1;
        const f32x4 q0 = mfma16(WqF0.b, ZA.b, z4);
        const f32x4 q1 = mfma16(WqF1.b, ZA.b, z4);
        const f32x4 g0 = mfma16(WgF0.b, ZA.b, z4);
        const f32x4 g1 = mfma16(WgF1.b, ZA.b, z4);
        QB[p2].u[0] = pk(q0[0]*k2e, q0[1]*k2e); QB[p2].u[1] = pk(q0[2]*k2e, q0[3]*k2e);
        QB[p2].u[2] = pk(q1[0]*k2e, q1[1]*k2e); QB[p2].u[3] = pk(q1[2]*k2e, q1[3]*k2e);
#pragma unroll
        for (int r = 0; r < 4; r++) {
          G[p2][r]     = 1.f / (1.f + __expf(-(g0[r] + bgl[r])));
          G[p2][4 + r] = 1.f / (1.f + __expf(-(g1[r] + bgl[4 + r])));
        }
      }
    }
    __syncthreads();
#pragma unroll
    for (int p2 = 0; p2 < 2; p2++) {
      float l = 0.f;
      f32x4 O0 = z4, O1 = z4;
#pragma unroll
      for (int kb = 0; kb < 256; kb += 32) {
        U8 KF0, KF1;
        {
          const uint2 a = *(const uint2*)&sK[kb + col][quad*4];
          const uint2 b = *(const uint2*)&sK[kb + col][16 + quad*4];
          KF0.u[0] = a.x; KF0.u[1] = a.y; KF0.u[2] = b.x; KF0.u[3] = b.y;
          const uint2 c = *(const uint2*)&sK[kb + 16 + col][quad*4];
          const uint2 d = *(const uint2*)&sK[kb + 16 + col][16 + quad*4];
          KF1.u[0] = c.x; KF1.u[1] = c.y; KF1.u[2] = d.x; KF1.u[3] = d.y;
        }
        const f32x4 S0 = mfma16(KF0.b, QB[p2].b, z4);
        const f32x4 S1 = mfma16(KF1.b, QB[p2].b, z4);
        float ps[8];
#pragma unroll
        for (int r = 0; r < 4; r++) {
          ps[r]     = __builtin_amdgcn_exp2f(S0[r]);
          ps[4 + r] = __builtin_amdgcn_exp2f(S1[r]);
        }
        l += ((ps[0] + ps[1]) + (ps[2] + ps[3])) + ((ps[4] + ps[5]) + (ps[6] + ps[7]));
        U8 PB;
        PB.u[0] = pk(ps[0], ps[1]); PB.u[1] = pk(ps[2], ps[3]);
        PB.u[2] = pk(ps[4], ps[5]); PB.u[3] = pk(ps[6], ps[7]);
        U8 VF0, VF1;
        {
          const uint2 a = *(const uint2*)&sVt[col][kb + quad*4];
          const uint2 b = *(const uint2*)&sVt[col][kb + 16 + quad*4];
          VF0.u[0] = a.x; VF0.u[1] = a.y; VF0.u[2] = b.x; VF0.u[3] = b.y;
          const uint2 c = *(const uint2*)&sVt[16 + col][kb + quad*4];
          const uint2 d = *(const uint2*)&sVt[16 + col][kb + 16 + quad*4];
          VF1.u[0] = c.x; VF1.u[1] = c.y; VF1.u[2] = d.x; VF1.u[3] = d.y;
        }
        O0 = mfma16(VF0.b, PB.b, O0);
        O1 = mfma16(VF1.b, PB.b, O1);
      }
      l += __shfl_xor(l, 16);
      l += __shfl_xor(l, 32);
      const float inv = 1.f / l;
      float og[8];
#pragma unroll
      for (int r = 0; r < 4; r++) {
        og[r]     = O0[r] * inv * G[p2][r];
        og[4 + r] = O1[r] * inv * G[p2][4 + r];
      }
      U8 OB;
      OB.u[0] = pk(og[0], og[1]); OB.u[1] = pk(og[2], og[3]);
      OB.u[2] = pk(og[4], og[5]); OB.u[3] = pk(og[6], og[7]);
      U8 WoA0, WoA1;
      {
        const float4 a = *(const float4*)(Wo + col*128 + h*32 + quad*4);
        const float4 b = *(const float4*)(Wo + col*128 + h*32 + 16 + quad*4);
        WoA0.u[0] = pk(a.x,a.y); WoA0.u[1] = pk(a.z,a.w);
        WoA0.u[2] = pk(b.x,b.y); WoA0.u[3] = pk(b.z,b.w);
        const float4 c = *(const float4*)(Wo + (16 + col)*128 + h*32 + quad*4);
        const float4 d = *(const float4*)(Wo + (16 + col)*128 + h*32 + 16 + quad*4);
        WoA1.u[0] = pk(c.x,c.y); WoA1.u[1] = pk(c.z,c.w);
        WoA1.u[2] = pk(d.x,d.y); WoA1.u[3] = pk(d.z,d.w);
      }
      acc[p2][0] = mfma16(WoA0.b, OB.b, acc[p2][0]);
      acc[p2][1] = mfma16(WoA1.b, OB.b, acc[p2][1]);
    }
    __syncthreads();
  }
  float bo0[4], bo1[4];
#pragma unroll
  for (int r = 0; r < 4; r++) {
    bo0[r] = bo[quad*4 + r];
    bo1[r] = bo[16 + quad*4 + r];
  }
#pragma unroll
  for (int p2 = 0; p2 < 2; p2++) {
    const int pos = (i << 8) + qhalf*128 + (p2*4 + wave)*16 + col;
    float* op = out + pos*32;
    *(float4*)(op + quad*4)      = make_float4(acc[p2][0][0] + bo0[0], acc[p2][0][1] + bo0[1],
                                               acc[p2][0][2] + bo0[2], acc[p2][0][3] + bo0[3]);
    *(float4*)(op + 16 + quad*4) = make_float4(acc[p2][1][0] + bo1[0], acc[p2][1][1] + bo1[1],
                                               acc[p2][1][2] + bo1[2], acc[p2][1][3] + bo1[3]);
  }
}

extern "C" void kernel_launch(void* const* d_in, const int* in_sizes, int n_in,
                              void* d_out, int out_size, void* d_ws, size_t ws_size,
                              hipStream_t stream)
{
  const float* z    = (const float*)d_in[0];
  const float* ln_g = (const float*)d_in[1];
  const float* ln_b = (const float*)d_in[2];
  const float* Wq   = (const float*)d_in[3];
  const float* Wk   = (const float*)d_in[4];
  const float* Wv   = (const float*)d_in[5];
  // d_in[6] = Wb: softmax shift invariance -> exactly cancels, unused.
  const float* Wg   = (const float*)d_in[7];
  const float* bg   = (const float*)d_in[8];
  const float* Wo   = (const float*)d_in[9];
  const float* bo   = (const float*)d_in[10];

  const size_t need = (size_t)4 * 65536 * 32 * sizeof(u16);   // 16 MiB go[h][pos][32]
  if (ws_size >= need) {
    u16* go = (u16*)d_ws;
    tri_attn_k1<<<dim3(4, 256), 256, 0, stream>>>(z, ln_g, ln_b, Wq, Wk, Wv, Wg, bg, go);
    tri_out_proj<<<dim3(1024), 256, 0, stream>>>(go, Wo, bo, (float*)d_out);
  } else {
    tri_attn_fused<<<dim3(2, 256), 256, 0, stream>>>(z, ln_g, ln_b, Wq, Wk, Wv, Wg, bg, Wo, bo,
                                                     (float*)d_out);
  }
}

// Round 8
// 128.200 us; speedup vs baseline: 1.6156x; 1.1503x over previous
//
#include <hip/hip_runtime.h>

// TriangleAttentionStartingNode — MI355X gfx950. f32 global I/O, bf16 MFMA compute.
//
// R8: zero-workspace fused kernel, 4 blocks/CU. R6/R7 proved every lane-store
// to d_ws costs a full 128-B HBM line (8B->16x, 16B->8x amplification; same
// pattern to d_out = 1.0x) => ws is unusable for bulk traffic. This round:
// query-quarter split, grid (qq=4, i=256)=1024 blocks; per block: LN once
// (shuffle stats, ZA[4] kept in regs across heads), per head {K/V proj of all
// 256 keys -> LDS (R4's measured-low-conflict b64 scheme); Q,G for own 64
// queries; S^T flash (scale*log2e folded into Q, no max, native exp2); gated
// O^T re-used as permuted-k B-frag vs Wo A-frags -> fp32 acc across heads};
// float4 epilogue to d_out (+bo).
//
// Wb (d_in[6]) unused: bias broadcasts along the softmax axis and cancels
// exactly (softmax shift invariance).

typedef unsigned short u16;
typedef unsigned int   u32;
typedef __bf16 bf16x8 __attribute__((ext_vector_type(8)));
typedef float  f32x4  __attribute__((ext_vector_type(4)));

union U8 { bf16x8 b; u32 u[4]; uint4 q; };

// round-half-up f32->bf16 pair pack: 2 adds + 1 v_perm
__device__ __forceinline__ u32 pk(float a, float b) {
  const u32 au = __float_as_uint(a) + 0x8000u;
  const u32 bu = __float_as_uint(b) + 0x8000u;
  return __builtin_amdgcn_perm(bu, au, 0x07060302u);  // {b.hi16, a.hi16}
}
__device__ __forceinline__ float lo16(u32 v) { return __uint_as_float(v << 16); }
__device__ __forceinline__ float hi16(u32 v) { return __uint_as_float(v & 0xffff0000u); }
__device__ __forceinline__ f32x4 mfma16(bf16x8 a, bf16x8 b, f32x4 c) {
  return __builtin_amdgcn_mfma_f32_16x16x32_bf16(a, b, c, 0, 0, 0);
}

#define LDK 36    // 72 B rows — b64 scheme, measured low-conflict (R4)
#define LDV 260   // 520 B rows — b64 scheme, measured low-conflict (R4)

__global__ __launch_bounds__(256, 4) void tri_attn_fused4(
    const float* __restrict__ z,  const float* __restrict__ ln_g, const float* __restrict__ ln_b,
    const float* __restrict__ Wq, const float* __restrict__ Wk,   const float* __restrict__ Wv,
    const float* __restrict__ Wg, const float* __restrict__ bg,
    const float* __restrict__ Wo, const float* __restrict__ bo,   float* __restrict__ out)
{
  __shared__ u16 sK [256][LDK];   // K[key][ch]    bf16 (per head)
  __shared__ u16 sVt[32][LDV];    // V^T[ch][key]  bf16 (per head)

  const int qq   = blockIdx.x;            // query quarter (64 queries)
  const int i    = blockIdx.y;
  const int tid  = threadIdx.x;
  const int wave = tid >> 6, lane = tid & 63, quad = lane >> 4, col = lane & 15;
  const f32x4 z4 = {0.f, 0.f, 0.f, 0.f};

  // per-lane LN params for channels quad*8..+7
  float lg[8], lb[8];
  {
    const float4 g0 = *(const float4*)(ln_g + quad*8);
    const float4 g1 = *(const float4*)(ln_g + quad*8 + 4);
    const float4 b0 = *(const float4*)(ln_b + quad*8);
    const float4 b1 = *(const float4*)(ln_b + quad*8 + 4);
    lg[0]=g0.x; lg[1]=g0.y; lg[2]=g0.z; lg[3]=g0.w; lg[4]=g1.x; lg[5]=g1.y; lg[6]=g1.z; lg[7]=g1.w;
    lb[0]=b0.x; lb[1]=b0.y; lb[2]=b0.z; lb[3]=b0.w; lb[4]=b1.x; lb[5]=b1.y; lb[6]=b1.z; lb[7]=b1.w;
  }

  // ------------- hoisted LN: zn fragments for all 4 p-tiles, in regs -------------
  U8 ZA[4];
#pragma unroll
  for (int p = 0; p < 4; p++) {
    const int pos = (p*4 + wave) * 16 + col;
    float x[8];
    {
      const float* zr = z + (((i << 8) + pos) << 5) + quad*8;
      const float4 a = *(const float4*)(zr);
      const float4 b = *(const float4*)(zr + 4);
      x[0]=a.x; x[1]=a.y; x[2]=a.z; x[3]=a.w; x[4]=b.x; x[5]=b.y; x[6]=b.z; x[7]=b.w;
    }
    float sx = 0.f, sq = 0.f;
#pragma unroll
    for (int e = 0; e < 8; e++) { sx += x[e]; sq = fmaf(x[e], x[e], sq); }
    sx += __shfl_xor(sx, 16);  sq += __shfl_xor(sq, 16);
    sx += __shfl_xor(sx, 32);  sq += __shfl_xor(sq, 32);
    const float mu   = sx * (1.f / 32.f);
    const float var  = sq * (1.f / 32.f) - mu * mu;
    const float rstd = rsqrtf(var + 1e-5f);
#pragma unroll
    for (int e = 0; e < 4; e++) {
      ZA[p].u[e] = pk((x[2*e]   - mu) * rstd * lg[2*e]   + lb[2*e],
                      (x[2*e+1] - mu) * rstd * lg[2*e+1] + lb[2*e+1]);
    }
  }

  const float k2e = 0.17677669529663687f * 1.44269504089f;   // (1/sqrt32)*log2(e)
  f32x4 acc0 = z4, acc1 = z4;   // fp32 out accumulators across heads
  U8  QB;                       // pre-scaled Q, permuted-k B-frag (own tile)
  u32 G16[4];                   // gates, packed bf16 pairs, O^T C-layout order

  for (int h = 0; h < 4; ++h) {
    // weight fragments for this head (L2-hot after first wave of blocks)
    auto ldw = [&](const float* W, int cb) -> U8 {
      const float* p = W + h*1024 + (cb*16 + col)*32 + quad*8;
      const float4 a = *(const float4*)(p);
      const float4 b = *(const float4*)(p + 4);
      U8 t;
      t.u[0] = pk(a.x, a.y); t.u[1] = pk(a.z, a.w);
      t.u[2] = pk(b.x, b.y); t.u[3] = pk(b.z, b.w);
      return t;
    };
    const U8 WkF0 = ldw(Wk,0), WkF1 = ldw(Wk,1);
    const U8 WvF0 = ldw(Wv,0), WvF1 = ldw(Wv,1);
    const U8 WqF0 = ldw(Wq,0), WqF1 = ldw(Wq,1);
    const U8 WgF0 = ldw(Wg,0), WgF1 = ldw(Wg,1);

    // -------------- phase 1: projections (K,V all 256 keys; Q,G own tile) --------------
#pragma unroll
    for (int p = 0; p < 4; p++) {
      const int pbase = (p*4 + wave) * 16, pos = pbase + col;
      const f32x4 k0 = mfma16(WkF0.b, ZA[p].b, z4);   // K^T: ch=quad*4+r,  pos=col
      const f32x4 k1 = mfma16(WkF1.b, ZA[p].b, z4);   //      ch=16+quad*4+r
      const f32x4 v0 = mfma16(ZA[p].b, WvF0.b, z4);   // V:   pos=quad*4+r, ch=col
      const f32x4 v1 = mfma16(ZA[p].b, WvF1.b, z4);   //                    ch=16+col
      *(uint2*)&sK[pos][quad*4]               = make_uint2(pk(k0[0],k0[1]), pk(k0[2],k0[3]));
      *(uint2*)&sK[pos][16 + quad*4]          = make_uint2(pk(k1[0],k1[1]), pk(k1[2],k1[3]));
      *(uint2*)&sVt[col][pbase + quad*4]      = make_uint2(pk(v0[0],v0[1]), pk(v0[2],v0[3]));
      *(uint2*)&sVt[16 + col][pbase + quad*4] = make_uint2(pk(v1[0],v1[1]), pk(v1[2],v1[3]));
      if (p == qq) {                          // own q-tile: Q and gate
        const f32x4 q0 = mfma16(WqF0.b, ZA[p].b, z4);
        const f32x4 q1 = mfma16(WqF1.b, ZA[p].b, z4);
        const f32x4 g0 = mfma16(WgF0.b, ZA[p].b, z4);
        const f32x4 g1 = mfma16(WgF1.b, ZA[p].b, z4);
        QB.u[0] = pk(q0[0]*k2e, q0[1]*k2e); QB.u[1] = pk(q0[2]*k2e, q0[3]*k2e);
        QB.u[2] = pk(q1[0]*k2e, q1[1]*k2e); QB.u[3] = pk(q1[2]*k2e, q1[3]*k2e);
        const float b0 = bg[h*32 + quad*4],      b1 = bg[h*32 + quad*4 + 1];
        const float b2 = bg[h*32 + quad*4 + 2],  b3 = bg[h*32 + quad*4 + 3];
        const float b4 = bg[h*32 + 16 + quad*4],     b5 = bg[h*32 + 16 + quad*4 + 1];
        const float b6 = bg[h*32 + 16 + quad*4 + 2], b7 = bg[h*32 + 16 + quad*4 + 3];
        G16[0] = pk(1.f/(1.f+__expf(-(g0[0]+b0))), 1.f/(1.f+__expf(-(g0[1]+b1))));
        G16[1] = pk(1.f/(1.f+__expf(-(g0[2]+b2))), 1.f/(1.f+__expf(-(g0[3]+b3))));
        G16[2] = pk(1.f/(1.f+__expf(-(g1[0]+b4))), 1.f/(1.f+__expf(-(g1[1]+b5))));
        G16[3] = pk(1.f/(1.f+__expf(-(g1[2]+b6))), 1.f/(1.f+__expf(-(g1[3]+b7))));
      }
    }
    __syncthreads();

    // -------------- phase 2: S^T flash on own 16-query tile --------------
    float l = 0.f;
    f32x4 O0 = z4, O1 = z4;                 // O^T: ch=quad*4+r (+16), q=col
#pragma unroll
    for (int kb = 0; kb < 256; kb += 32) {
      U8 KF0, KF1;
      {
        const uint2 a = *(const uint2*)&sK[kb + col][quad*4];
        const uint2 b = *(const uint2*)&sK[kb + col][16 + quad*4];
        KF0.u[0] = a.x; KF0.u[1] = a.y; KF0.u[2] = b.x; KF0.u[3] = b.y;
        const uint2 c = *(const uint2*)&sK[kb + 16 + col][quad*4];
        const uint2 d = *(const uint2*)&sK[kb + 16 + col][16 + quad*4];
        KF1.u[0] = c.x; KF1.u[1] = c.y; KF1.u[2] = d.x; KF1.u[3] = d.y;
      }
      const f32x4 S0 = mfma16(KF0.b, QB.b, z4);   // keys kb+quad*4+r
      const f32x4 S1 = mfma16(KF1.b, QB.b, z4);   // keys kb+16+quad*4+r
      float ps[8];
#pragma unroll
      for (int r = 0; r < 4; r++) {
        ps[r]     = __builtin_amdgcn_exp2f(S0[r]);
        ps[4 + r] = __builtin_amdgcn_exp2f(S1[r]);
      }
      l += ((ps[0] + ps[1]) + (ps[2] + ps[3])) + ((ps[4] + ps[5]) + (ps[6] + ps[7]));
      U8 PB;
      PB.u[0] = pk(ps[0], ps[1]); PB.u[1] = pk(ps[2], ps[3]);
      PB.u[2] = pk(ps[4], ps[5]); PB.u[3] = pk(ps[6], ps[7]);
      U8 VF0, VF1;
      {
        const uint2 a = *(const uint2*)&sVt[col][kb + quad*4];
        const uint2 b = *(const uint2*)&sVt[col][kb + 16 + quad*4];
        VF0.u[0] = a.x; VF0.u[1] = a.y; VF0.u[2] = b.x; VF0.u[3] = b.y;
        const uint2 c = *(const uint2*)&sVt[16 + col][kb + quad*4];
        const uint2 d = *(const uint2*)&sVt[16 + col][kb + 16 + quad*4];
        VF1.u[0] = c.x; VF1.u[1] = c.y; VF1.u[2] = d.x; VF1.u[3] = d.y;
      }
      O0 = mfma16(VF0.b, PB.b, O0);
      O1 = mfma16(VF1.b, PB.b, O1);
    }
    l += __shfl_xor(l, 16);
    l += __shfl_xor(l, 32);
    const float inv = __builtin_amdgcn_rcpf(l);
    float og[8];
    og[0] = O0[0]*inv*lo16(G16[0]); og[1] = O0[1]*inv*hi16(G16[0]);
    og[2] = O0[2]*inv*lo16(G16[1]); og[3] = O0[3]*inv*hi16(G16[1]);
    og[4] = O1[0]*inv*lo16(G16[2]); og[5] = O1[1]*inv*hi16(G16[2]);
    og[6] = O1[2]*inv*lo16(G16[3]); og[7] = O1[3]*inv*hi16(G16[3]);
    U8 OB;   // gated O^T as permuted-k B-frag (sigma over head channels)
    OB.u[0] = pk(og[0], og[1]); OB.u[1] = pk(og[2], og[3]);
    OB.u[2] = pk(og[4], og[5]); OB.u[3] = pk(og[6], og[7]);
    // Wo A-frags with matching sigma permutation
    U8 WoA0, WoA1;
    {
      const float4 a = *(const float4*)(Wo + col*128 + h*32 + quad*4);
      const float4 b = *(const float4*)(Wo + col*128 + h*32 + 16 + quad*4);
      WoA0.u[0] = pk(a.x,a.y); WoA0.u[1] = pk(a.z,a.w);
      WoA0.u[2] = pk(b.x,b.y); WoA0.u[3] = pk(b.z,b.w);
      const float4 c = *(const float4*)(Wo + (16 + col)*128 + h*32 + quad*4);
      const float4 d = *(const float4*)(Wo + (16 + col)*128 + h*32 + 16 + quad*4);
      WoA1.u[0] = pk(c.x,c.y); WoA1.u[1] = pk(c.z,c.w);
      WoA1.u[2] = pk(d.x,d.y); WoA1.u[3] = pk(d.z,d.w);
    }
    acc0 = mfma16(WoA0.b, OB.b, acc0);   // couts 0..15
    acc1 = mfma16(WoA1.b, OB.b, acc1);   // couts 16..31
    __syncthreads();   // protect sK/sVt before next head overwrites
  }

  // ---------------- epilogue: + bo, float4 stores to d_out ----------------
  float bo0[4], bo1[4];
#pragma unroll
  for (int r = 0; r < 4; r++) {
    bo0[r] = bo[quad*4 + r];
    bo1[r] = bo[16 + quad*4 + r];
  }
  const int pos = (i << 8) + (qq*4 + wave)*16 + col;
  float* op = out + pos*32;
  *(float4*)(op + quad*4)      = make_float4(acc0[0] + bo0[0], acc0[1] + bo0[1],
                                             acc0[2] + bo0[2], acc0[3] + bo0[3]);
  *(float4*)(op + 16 + quad*4) = make_float4(acc1[0] + bo1[0], acc1[1] + bo1[1],
                                             acc1[2] + bo1[2], acc1[3] + bo1[3]);
}

extern "C" void kernel_launch(void* const* d_in, const int* in_sizes, int n_in,
                              void* d_out, int out_size, void* d_ws, size_t ws_size,
                              hipStream_t stream)
{
  const float* z    = (const float*)d_in[0];
  const float* ln_g = (const float*)d_in[1];
  const float* ln_b = (const float*)d_in[2];
  const float* Wq   = (const float*)d_in[3];
  const float* Wk   = (const float*)d_in[4];
  const float* Wv   = (const float*)d_in[5];
  // d_in[6] = Wb: softmax shift invariance -> exactly cancels, unused.
  const float* Wg   = (const float*)d_in[7];
  const float* bg   = (const float*)d_in[8];
  const float* Wo   = (const float*)d_in[9];
  const float* bo   = (const float*)d_in[10];

  tri_attn_fused4<<<dim3(4, 256), 256, 0, stream>>>(z, ln_g, ln_b, Wq, Wk, Wv, Wg, bg, Wo, bo,
                                                    (float*)d_out);
}